// Round 1
// baseline (1495.936 us; speedup 1.0000x reference)
//
#include <hip/hip_runtime.h>
#include <hip/hip_bf16.h>

#define N_IND 1000000
#define N_ORG 300000
#define N_EXT 100000
#define F 64
#define E_PER 1000000
#define NREL 14

// ---- workspace layout (in floats) ----
// sc_ind: float2[7][N_IND]  -> 14,000,000 floats at off 0
// sc_org: float2[7][N_ORG]  ->  4,200,000 floats
// p_ind : [5][N_IND]        ->  5,000,000
// p_org : [5][N_ORG]        ->  1,500,000
// p_ext : [4][N_EXT]        ->    400,000
// base_ind: [N_IND]
// base_org: [N_ORG]
// wm_ind[6*64], wm_org[6*64], wm_ext[4*64], bsum[2]
static const size_t OFF_SC_IND   = 0;
static const size_t OFF_SC_ORG   = 14000000;
static const size_t OFF_P_IND    = 18200000;
static const size_t OFF_P_ORG    = 23200000;
static const size_t OFF_P_EXT    = 24700000;
static const size_t OFF_BASE_IND = 25100000;
static const size_t OFF_BASE_ORG = 26100000;
static const size_t OFF_WM_IND   = 26400000; // 6*64
static const size_t OFF_WM_ORG   = 26400384; // 6*64
static const size_t OFF_WM_EXT   = 26400768; // 4*64
static const size_t OFF_BSUM     = 26401024; // 2
static const size_t WS_FLOATS    = 26401026;

// Build packed weight matrices + combined Wr/b per dst type.
__global__ void prep_kernel(const float* __restrict__ Wl,
                            const float* __restrict__ Wr,
                            const float* __restrict__ b,
                            float* __restrict__ wm_ind,
                            float* __restrict__ wm_org,
                            float* __restrict__ wm_ext,
                            float* __restrict__ bsum) {
    int t = threadIdx.x; // 64 threads
    const int ind_wl[5] = {0, 3, 6, 7, 10};   // rels with src=ind (p_ind slots 0..4)
    const int org_wl[5] = {1, 4, 8, 11, 13};  // src=org
    const int ext_wl[4] = {2, 5, 9, 12};      // src=ext
    const int ind_r[7]  = {0, 1, 2, 7, 8, 9, 13};   // rels with dst=ind
    const int org_r[7]  = {3, 4, 5, 6, 10, 11, 12}; // dst=org
#pragma unroll
    for (int k = 0; k < 5; ++k) wm_ind[k * 64 + t] = Wl[ind_wl[k] * 64 + t];
#pragma unroll
    for (int k = 0; k < 5; ++k) wm_org[k * 64 + t] = Wl[org_wl[k] * 64 + t];
#pragma unroll
    for (int k = 0; k < 4; ++k) wm_ext[k * 64 + t] = Wl[ext_wl[k] * 64 + t];
    float si = 0.f, so = 0.f;
#pragma unroll
    for (int k = 0; k < 7; ++k) {
        si += Wr[ind_r[k] * 64 + t];
        so += Wr[org_r[k] * 64 + t];
    }
    wm_ind[5 * 64 + t] = si;
    wm_org[5 * 64 + t] = so;
    if (t == 0) {
        float bi = 0.f, bo = 0.f;
#pragma unroll
        for (int k = 0; k < 7; ++k) { bi += b[ind_r[k]]; bo += b[org_r[k]]; }
        bsum[0] = bi;
        bsum[1] = bo;
    }
}

// Per-node rank-1 projections: K dots per node. If HASBASE, last dot is the
// combined Wr projection -> base_out (+bsum). Weights are wave-uniform -> s_load.
template <int K, bool HASBASE>
__global__ __launch_bounds__(256) void proj_kernel(
    const float* __restrict__ x, int n,
    const float* __restrict__ wm,
    float* __restrict__ p,            // [K or K-1][n]
    float* __restrict__ base_out,     // null if !HASBASE
    const float* __restrict__ bsum) { // points at the right scalar
    int i = blockIdx.x * 256 + threadIdx.x;
    if (i >= n) return;
    const float4* xv = (const float4*)(x + (size_t)i * F);
    float acc[K];
#pragma unroll
    for (int k = 0; k < K; ++k) acc[k] = 0.f;
#pragma unroll
    for (int c = 0; c < 16; ++c) {
        float4 v = xv[c];
#pragma unroll
        for (int k = 0; k < K; ++k) {
            const float* w = wm + k * 64 + c * 4;
            acc[k] += v.x * w[0] + v.y * w[1] + v.z * w[2] + v.w * w[3];
        }
    }
    constexpr int NP = HASBASE ? K - 1 : K;
#pragma unroll
    for (int k = 0; k < NP; ++k) p[(size_t)k * n + i] = acc[k];
    if (HASBASE) base_out[i] = acc[K - 1] + bsum[0];
}

// One thread per edge; blockIdx.y = relation. Gather scalar p[src], scatter
// (sum, cnt) atomics into the per-relation slot of the dst-type accumulator.
__global__ __launch_bounds__(256) void edge_kernel(
    const int* __restrict__ ei, // [14][2][E]
    const float* __restrict__ p_ind,
    const float* __restrict__ p_org,
    const float* __restrict__ p_ext,
    float2* __restrict__ sc_ind,
    float2* __restrict__ sc_org) {
    const int r = blockIdx.y;
    const int e = blockIdx.x * 256 + threadIdx.x;
    if (e >= E_PER) return;
    // relation tables (r is wave-uniform -> scalar)
    const int srcType[NREL] = {0,1,2,0,1,2,0,0,1,2,0,1,2,1};
    const int srcSlot[NREL] = {0,0,0,1,1,1,2,3,2,2,4,3,3,4};
    const int dstType[NREL] = {0,0,0,1,1,1,1,0,0,0,1,1,1,0};
    const int dstSlot[NREL] = {0,1,2,0,1,2,3,3,4,5,4,5,6,6};

    const int src = ei[((size_t)r * 2 + 0) * E_PER + e];
    const int dst = ei[((size_t)r * 2 + 1) * E_PER + e];

    float pv;
    const int st = srcType[r];
    if (st == 0)      pv = p_ind[(size_t)srcSlot[r] * N_IND + src];
    else if (st == 1) pv = p_org[(size_t)srcSlot[r] * N_ORG + src];
    else              pv = p_ext[(size_t)srcSlot[r] * N_EXT + src];

    float2* sc = (dstType[r] == 0) ? (sc_ind + (size_t)dstSlot[r] * N_IND)
                                   : (sc_org + (size_t)dstSlot[r] * N_ORG);
    atomicAdd(&sc[dst].x, pv);
    atomicAdd(&sc[dst].y, 1.0f);
}

// out = sigmoid(base + sum_slots sum/max(cnt,1))
__global__ __launch_bounds__(256) void final_kernel(
    const float2* __restrict__ sc, const float* __restrict__ base, int n,
    float* __restrict__ out) {
    int i = blockIdx.x * 256 + threadIdx.x;
    if (i >= n) return;
    float acc = base[i];
#pragma unroll
    for (int s = 0; s < 7; ++s) {
        float2 v = sc[(size_t)s * n + i];
        acc += v.x / fmaxf(v.y, 1.0f);
    }
    out[i] = 1.0f / (1.0f + __expf(-acc));
}

extern "C" void kernel_launch(void* const* d_in, const int* in_sizes, int n_in,
                              void* d_out, int out_size, void* d_ws, size_t ws_size,
                              hipStream_t stream) {
    const float* x_ind = (const float*)d_in[0];
    const float* x_org = (const float*)d_in[1];
    const float* x_ext = (const float*)d_in[2];
    const float* Wl    = (const float*)d_in[3];
    const float* Wr    = (const float*)d_in[4];
    const float* b     = (const float*)d_in[5];
    const int*   ei    = (const int*)d_in[6];
    float* out = (float*)d_out;

    float* ws = (float*)d_ws;
    float2* sc_ind = (float2*)(ws + OFF_SC_IND);
    float2* sc_org = (float2*)(ws + OFF_SC_ORG);
    float* p_ind   = ws + OFF_P_IND;
    float* p_org   = ws + OFF_P_ORG;
    float* p_ext   = ws + OFF_P_EXT;
    float* base_ind = ws + OFF_BASE_IND;
    float* base_org = ws + OFF_BASE_ORG;
    float* wm_ind  = ws + OFF_WM_IND;
    float* wm_org  = ws + OFF_WM_ORG;
    float* wm_ext  = ws + OFF_WM_EXT;
    float* bsum    = ws + OFF_BSUM;

    // zero the (sum,cnt) accumulators — 72.8 MB
    hipMemsetAsync(ws + OFF_SC_IND, 0, (OFF_P_IND - OFF_SC_IND) * sizeof(float), stream);

    prep_kernel<<<1, 64, 0, stream>>>(Wl, Wr, b, wm_ind, wm_org, wm_ext, bsum);

    proj_kernel<6, true><<<(N_IND + 255) / 256, 256, 0, stream>>>(
        x_ind, N_IND, wm_ind, p_ind, base_ind, bsum + 0);
    proj_kernel<6, true><<<(N_ORG + 255) / 256, 256, 0, stream>>>(
        x_org, N_ORG, wm_org, p_org, base_org, bsum + 1);
    proj_kernel<4, false><<<(N_EXT + 255) / 256, 256, 0, stream>>>(
        x_ext, N_EXT, wm_ext, p_ext, nullptr, bsum);

    dim3 egrid((E_PER + 255) / 256, NREL);
    edge_kernel<<<egrid, 256, 0, stream>>>(ei, p_ind, p_org, p_ext, sc_ind, sc_org);

    final_kernel<<<(N_IND + 255) / 256, 256, 0, stream>>>(sc_ind, base_ind, N_IND, out);
    final_kernel<<<(N_ORG + 255) / 256, 256, 0, stream>>>(sc_org, base_org, N_ORG, out + N_IND);
}

// Round 2
// 746.644 us; speedup vs baseline: 2.0035x; 2.0035x over previous
//
#include <hip/hip_runtime.h>
#include <hip/hip_bf16.h>

#define N_IND 1000000
#define N_ORG 300000
#define N_EXT 100000
#define F 64
#define E_PER 1000000
#define NREL 14

// ---- workspace layout ----
// sc_ind: double[7][N_IND]  (packed cnt*2^32 + sum)
// sc_org: double[7][N_ORG]
// then float arrays: p_ind[5][N_IND], p_org[5][N_ORG], p_ext[4][N_EXT],
// base_ind[N_IND], base_org[N_ORG], wm_*[...], bsum[2]
// Offsets below are in FLOAT units (doubles occupy 2 floats; same byte layout
// as the previous float2 version).
static const size_t OFF_SC_IND   = 0;          // 7*N_IND doubles = 14e6 floats
static const size_t OFF_SC_ORG   = 14000000;   // 7*N_ORG doubles = 4.2e6 floats
static const size_t OFF_P_IND    = 18200000;
static const size_t OFF_P_ORG    = 23200000;
static const size_t OFF_P_EXT    = 24700000;
static const size_t OFF_BASE_IND = 25100000;
static const size_t OFF_BASE_ORG = 26100000;
static const size_t OFF_WM_IND   = 26400000; // 6*64
static const size_t OFF_WM_ORG   = 26400384; // 6*64
static const size_t OFF_WM_EXT   = 26400768; // 4*64
static const size_t OFF_BSUM     = 26401024; // 2

#define CNT_SCALE 4294967296.0           // 2^32
#define CNT_INV   2.3283064365386963e-10 // 2^-32

// Build packed weight matrices + combined Wr/b per dst type.
__global__ void prep_kernel(const float* __restrict__ Wl,
                            const float* __restrict__ Wr,
                            const float* __restrict__ b,
                            float* __restrict__ wm_ind,
                            float* __restrict__ wm_org,
                            float* __restrict__ wm_ext,
                            float* __restrict__ bsum) {
    int t = threadIdx.x; // 64 threads
    const int ind_wl[5] = {0, 3, 6, 7, 10};   // rels with src=ind (p_ind slots 0..4)
    const int org_wl[5] = {1, 4, 8, 11, 13};  // src=org
    const int ext_wl[4] = {2, 5, 9, 12};      // src=ext
    const int ind_r[7]  = {0, 1, 2, 7, 8, 9, 13};   // rels with dst=ind
    const int org_r[7]  = {3, 4, 5, 6, 10, 11, 12}; // dst=org
#pragma unroll
    for (int k = 0; k < 5; ++k) wm_ind[k * 64 + t] = Wl[ind_wl[k] * 64 + t];
#pragma unroll
    for (int k = 0; k < 5; ++k) wm_org[k * 64 + t] = Wl[org_wl[k] * 64 + t];
#pragma unroll
    for (int k = 0; k < 4; ++k) wm_ext[k * 64 + t] = Wl[ext_wl[k] * 64 + t];
    float si = 0.f, so = 0.f;
#pragma unroll
    for (int k = 0; k < 7; ++k) {
        si += Wr[ind_r[k] * 64 + t];
        so += Wr[org_r[k] * 64 + t];
    }
    wm_ind[5 * 64 + t] = si;
    wm_org[5 * 64 + t] = so;
    if (t == 0) {
        float bi = 0.f, bo = 0.f;
#pragma unroll
        for (int k = 0; k < 7; ++k) { bi += b[ind_r[k]]; bo += b[org_r[k]]; }
        bsum[0] = bi;
        bsum[1] = bo;
    }
}

// Per-node rank-1 projections: K dots per node. If HASBASE, last dot is the
// combined Wr projection -> base_out (+bsum). Weights are wave-uniform -> s_load.
template <int K, bool HASBASE>
__global__ __launch_bounds__(256) void proj_kernel(
    const float* __restrict__ x, int n,
    const float* __restrict__ wm,
    float* __restrict__ p,            // [K or K-1][n]
    float* __restrict__ base_out,     // null if !HASBASE
    const float* __restrict__ bsum) { // points at the right scalar
    int i = blockIdx.x * 256 + threadIdx.x;
    if (i >= n) return;
    const float4* xv = (const float4*)(x + (size_t)i * F);
    float acc[K];
#pragma unroll
    for (int k = 0; k < K; ++k) acc[k] = 0.f;
#pragma unroll
    for (int c = 0; c < 16; ++c) {
        float4 v = xv[c];
#pragma unroll
        for (int k = 0; k < K; ++k) {
            const float* w = wm + k * 64 + c * 4;
            acc[k] += v.x * w[0] + v.y * w[1] + v.z * w[2] + v.w * w[3];
        }
    }
    constexpr int NP = HASBASE ? K - 1 : K;
#pragma unroll
    for (int k = 0; k < NP; ++k) p[(size_t)k * n + i] = acc[k];
    if (HASBASE) base_out[i] = acc[K - 1] + bsum[0];
}

// One thread per edge; blockIdx.y = relation. Gather scalar p[src], one packed
// f64 atomic (cnt*2^32 + sum) into the per-relation slot of the dst-type acc.
__global__ __launch_bounds__(256) void edge_kernel(
    const int* __restrict__ ei, // [14][2][E]
    const float* __restrict__ p_ind,
    const float* __restrict__ p_org,
    const float* __restrict__ p_ext,
    double* __restrict__ sc_ind,
    double* __restrict__ sc_org) {
    const int r = blockIdx.y;
    const int e = blockIdx.x * 256 + threadIdx.x;
    if (e >= E_PER) return;
    // relation tables (r is wave-uniform -> scalar)
    const int srcType[NREL] = {0,1,2,0,1,2,0,0,1,2,0,1,2,1};
    const int srcSlot[NREL] = {0,0,0,1,1,1,2,3,2,2,4,3,3,4};
    const int dstType[NREL] = {0,0,0,1,1,1,1,0,0,0,1,1,1,0};
    const int dstSlot[NREL] = {0,1,2,0,1,2,3,3,4,5,4,5,6,6};

    const int src = ei[((size_t)r * 2 + 0) * E_PER + e];
    const int dst = ei[((size_t)r * 2 + 1) * E_PER + e];

    float pv;
    const int st = srcType[r];
    if (st == 0)      pv = p_ind[(size_t)srcSlot[r] * N_IND + src];
    else if (st == 1) pv = p_org[(size_t)srcSlot[r] * N_ORG + src];
    else              pv = p_ext[(size_t)srcSlot[r] * N_EXT + src];

    double* sc = (dstType[r] == 0) ? (sc_ind + (size_t)dstSlot[r] * N_IND)
                                   : (sc_org + (size_t)dstSlot[r] * N_ORG);
    unsafeAtomicAdd(&sc[dst], (double)pv + CNT_SCALE);
}

// out = sigmoid(base + sum_slots sum/max(cnt,1)), unpacking cnt*2^32+sum.
__global__ __launch_bounds__(256) void final_kernel(
    const double* __restrict__ sc, const float* __restrict__ base, int n,
    float* __restrict__ out) {
    int i = blockIdx.x * 256 + threadIdx.x;
    if (i >= n) return;
    float acc = base[i];
#pragma unroll
    for (int s = 0; s < 7; ++s) {
        double x = sc[(size_t)s * n + i];
        double c = floor(x * CNT_INV + 0.5);
        double sum = x - c * CNT_SCALE;
        acc += (float)sum / fmaxf((float)c, 1.0f);
    }
    out[i] = 1.0f / (1.0f + __expf(-acc));
}

extern "C" void kernel_launch(void* const* d_in, const int* in_sizes, int n_in,
                              void* d_out, int out_size, void* d_ws, size_t ws_size,
                              hipStream_t stream) {
    const float* x_ind = (const float*)d_in[0];
    const float* x_org = (const float*)d_in[1];
    const float* x_ext = (const float*)d_in[2];
    const float* Wl    = (const float*)d_in[3];
    const float* Wr    = (const float*)d_in[4];
    const float* b     = (const float*)d_in[5];
    const int*   ei    = (const int*)d_in[6];
    float* out = (float*)d_out;

    float* ws = (float*)d_ws;
    double* sc_ind = (double*)(ws + OFF_SC_IND);
    double* sc_org = (double*)(ws + OFF_SC_ORG);
    float* p_ind   = ws + OFF_P_IND;
    float* p_org   = ws + OFF_P_ORG;
    float* p_ext   = ws + OFF_P_EXT;
    float* base_ind = ws + OFF_BASE_IND;
    float* base_org = ws + OFF_BASE_ORG;
    float* wm_ind  = ws + OFF_WM_IND;
    float* wm_org  = ws + OFF_WM_ORG;
    float* wm_ext  = ws + OFF_WM_EXT;
    float* bsum    = ws + OFF_BSUM;

    // zero the packed accumulators — 72.8 MB
    hipMemsetAsync(ws + OFF_SC_IND, 0, (OFF_P_IND - OFF_SC_IND) * sizeof(float), stream);

    prep_kernel<<<1, 64, 0, stream>>>(Wl, Wr, b, wm_ind, wm_org, wm_ext, bsum);

    proj_kernel<6, true><<<(N_IND + 255) / 256, 256, 0, stream>>>(
        x_ind, N_IND, wm_ind, p_ind, base_ind, bsum + 0);
    proj_kernel<6, true><<<(N_ORG + 255) / 256, 256, 0, stream>>>(
        x_org, N_ORG, wm_org, p_org, base_org, bsum + 1);
    proj_kernel<4, false><<<(N_EXT + 255) / 256, 256, 0, stream>>>(
        x_ext, N_EXT, wm_ext, p_ext, nullptr, bsum);

    dim3 egrid((E_PER + 255) / 256, NREL);
    edge_kernel<<<egrid, 256, 0, stream>>>(ei, p_ind, p_org, p_ext, sc_ind, sc_org);

    final_kernel<<<(N_IND + 255) / 256, 256, 0, stream>>>(sc_ind, base_ind, N_IND, out);
    final_kernel<<<(N_ORG + 255) / 256, 256, 0, stream>>>(sc_org, base_org, N_ORG, out + N_IND);
}